// Round 2
// baseline (271.195 us; speedup 1.0000x reference)
//
#include <hip/hip_runtime.h>
#include <hip/hip_fp16.h>
#include <math.h>
#include <stdint.h>

#define BB 32
#define NN 512
#define DDIM 512
#define HH 8
#define DK 64

typedef __attribute__((ext_vector_type(8))) short short8;
typedef __attribute__((ext_vector_type(8))) _Float16 half8;
typedef __attribute__((ext_vector_type(2))) _Float16 half2v;
typedef __attribute__((ext_vector_type(4))) float floatx4;
typedef __attribute__((ext_vector_type(16))) float floatx16;
typedef unsigned short ushort_t;
typedef unsigned int uint_t;

// async global->LDS, 16B/lane; LDS dest = wave-uniform base + lane*16
__device__ __forceinline__ void gl_lds16(const void* g, void* l) {
    __builtin_amdgcn_global_load_lds(
        (const __attribute__((address_space(1))) uint_t*)g,
        (__attribute__((address_space(3))) uint_t*)l,
        16, 0, 0);
}

__device__ __forceinline__ ushort_t f2bf(float f) {  // RNE fp32->bf16
    uint_t u = __builtin_bit_cast(uint_t, f);
    u += 0x7fff + ((u >> 16) & 1);
    return (ushort_t)(u >> 16);
}

__device__ __forceinline__ uint_t pkbf(float a, float b) {
    return (uint_t)f2bf(a) | ((uint_t)f2bf(b) << 16);
}

__device__ __forceinline__ uint_t pkh(float a, float b) {  // 2xf32 -> f16x2 (RTZ, 1 inst)
    return __builtin_bit_cast(uint_t, __builtin_amdgcn_cvt_pkrtz(a, b));
}

__device__ __forceinline__ float h2f(ushort_t u) {
    return __half2float(__ushort_as_half(u));
}

// ---------------------------------------------------------------------------
// prep kernels
// ---------------------------------------------------------------------------
__global__ __launch_bounds__(256) void cvt_bf16(const float* __restrict__ s,
                                                ushort_t* __restrict__ d, int n8) {
    const int i = blockIdx.x * 256 + threadIdx.x;
    if (i >= n8) return;
    const float4 a = ((const float4*)s)[i * 2 + 0];
    const float4 b = ((const float4*)s)[i * 2 + 1];
    uint4 o;
    o.x = pkbf(a.x, a.y); o.y = pkbf(a.z, a.w);
    o.z = pkbf(b.x, b.y); o.w = pkbf(b.z, b.w);
    *(uint4*)(d + i * 8) = o;
}

__global__ __launch_bounds__(256) void cvt_w4(
    const float* __restrict__ w0, const float* __restrict__ w1,
    const float* __restrict__ w2, const float* __restrict__ w3,
    ushort_t* __restrict__ o0, ushort_t* __restrict__ o1,
    ushort_t* __restrict__ o2, ushort_t* __restrict__ o3) {
    const float* s; ushort_t* d;
    if (blockIdx.y == 0)      { s = w0; d = o0; }
    else if (blockIdx.y == 1) { s = w1; d = o1; }
    else if (blockIdx.y == 2) { s = w2; d = o2; }
    else                      { s = w3; d = o3; }
    const int i = blockIdx.x * 256 + threadIdx.x;
    const float4 a = ((const float4*)s)[i * 2 + 0];
    const float4 b = ((const float4*)s)[i * 2 + 1];
    uint4 o;
    o.x = pkbf(a.x, a.y); o.y = pkbf(a.z, a.w);
    o.z = pkbf(b.x, b.y); o.w = pkbf(b.z, b.w);
    *(uint4*)(d + i * 8) = o;
}

// distance -> fp16 T[bin] = (dw[bin]-3)*log2e  (constant-max softmax, base-2)
__global__ __launch_bounds__(256) void bias_half(const float* __restrict__ dist,
                                                 const float* __restrict__ dw,
                                                 ushort_t* __restrict__ T, int n8) {
    __shared__ float dws[21];
    if (threadIdx.x < 21) dws[threadIdx.x] = (dw[threadIdx.x] - 3.0f) * 1.44269504f;
    __syncthreads();
    const int i = blockIdx.x * 256 + threadIdx.x;
    if (i >= n8) return;
    float dv[8];
    { const float4 a = ((const float4*)dist)[i * 2 + 0];
      const float4 b = ((const float4*)dist)[i * 2 + 1];
      dv[0]=a.x; dv[1]=a.y; dv[2]=a.z; dv[3]=a.w;
      dv[4]=b.x; dv[5]=b.y; dv[6]=b.z; dv[7]=b.w; }
    ushort_t h[8];
    #pragma unroll
    for (int j = 0; j < 8; ++j) {
        int bin = (int)(dv[j] / 5.0f);
        bin = bin < 0 ? 0 : (bin > 20 ? 20 : bin);
        h[j] = __half_as_ushort(__float2half(dws[bin]));
    }
    uint4 o;
    o.x = (uint_t)h[0] | ((uint_t)h[1] << 16);
    o.y = (uint_t)h[2] | ((uint_t)h[3] << 16);
    o.z = (uint_t)h[4] | ((uint_t)h[5] << 16);
    o.w = (uint_t)h[6] | ((uint_t)h[7] << 16);
    *(uint4*)(T + i * 8) = o;
}

// V (fp16) [b][q][h*64+d] -> Vt [(b*8+h)*64+d][512]  (dtype-opaque transpose)
__global__ __launch_bounds__(256) void transp_v(const ushort_t* __restrict__ V,
                                                ushort_t* __restrict__ Vt) {
    __shared__ ushort_t T[64][72];
    const int tid = threadIdx.x;
    const int q0 = blockIdx.x * 64;
    const int bh = blockIdx.y, b = bh >> 3, h = bh & 7;
    #pragma unroll
    for (int rnd = 0; rnd < 2; ++rnd) {
        const int idx = rnd * 256 + tid;
        const int row = idx >> 3, c8 = (idx & 7) * 8;
        const uint4 v = *(const uint4*)&V[((size_t)(b * NN + q0 + row)) * DDIM + h * DK + c8];
        ushort_t* t = &T[row][c8];
        t[0] = (ushort_t)v.x; t[1] = (ushort_t)(v.x >> 16);
        t[2] = (ushort_t)v.y; t[3] = (ushort_t)(v.y >> 16);
        t[4] = (ushort_t)v.z; t[5] = (ushort_t)(v.z >> 16);
        t[6] = (ushort_t)v.w; t[7] = (ushort_t)(v.w >> 16);
    }
    __syncthreads();
    #pragma unroll
    for (int rnd = 0; rnd < 2; ++rnd) {
        const int idx = rnd * 256 + tid;
        const int d = idx >> 3, q8 = (idx & 7) * 8;
        uint4 o;
        o.x = (uint_t)T[q8 + 0][d] | ((uint_t)T[q8 + 1][d] << 16);
        o.y = (uint_t)T[q8 + 2][d] | ((uint_t)T[q8 + 3][d] << 16);
        o.z = (uint_t)T[q8 + 4][d] | ((uint_t)T[q8 + 5][d] << 16);
        o.w = (uint_t)T[q8 + 6][d] | ((uint_t)T[q8 + 7][d] << 16);
        *(uint4*)&Vt[((size_t)(bh * DK + d)) * NN + q0 + q8] = o;
    }
}

// ---------------------------------------------------------------------------
// GEMM core: D[feat][token] = W x A^T. 128x128 tile, BK=32, global_load_lds,
// XOR chunk swizzle.
// ---------------------------------------------------------------------------
#define GEMM_CORE(Aptr, Wptr)                                                           \
    __shared__ ushort_t As[128 * 32];                                                   \
    __shared__ ushort_t Bs[128 * 32];                                                   \
    const int tid = threadIdx.x;                                                        \
    const int lane = tid & 63, wid = tid >> 6;                                          \
    const int quad = lane >> 4, l15 = lane & 15;                                        \
    const int m0 = blockIdx.x * 128, n0 = blockIdx.y * 128;                             \
    const int wy = wid >> 1, wx = wid & 1;                                              \
    floatx4 acc[4][4];                                                                  \
    _Pragma("unroll") for (int i = 0; i < 4; ++i)                                       \
        _Pragma("unroll") for (int j = 0; j < 4; ++j)                                   \
            _Pragma("unroll") for (int r = 0; r < 4; ++r) acc[i][j][r] = 0.f;           \
    for (int k0 = 0; k0 < DDIM; k0 += 32) {                                             \
        __syncthreads();                                                                \
        _Pragma("unroll") for (int j = 0; j < 4; ++j) {                                 \
            const int t = wid * 4 + j;                                                  \
            const int rowi = ((t & 7) << 4) + (lane >> 2);                              \
            const int cd = (lane & 3) ^ ((rowi >> 1) & 3);                              \
            if (t < 8)                                                                  \
                gl_lds16(Aptr + (size_t)(m0 + rowi) * DDIM + k0 + cd * 8,               \
                         (char*)As + ((t & 7) << 10));                                  \
            else                                                                        \
                gl_lds16(Wptr + (size_t)(n0 + rowi) * DDIM + k0 + cd * 8,               \
                         (char*)Bs + ((t & 7) << 10));                                  \
        }                                                                               \
        __syncthreads();                                                                \
        short8 aw[4], bt[4];                                                            \
        _Pragma("unroll") for (int fi = 0; fi < 4; ++fi) {                              \
            const int r = wy * 64 + fi * 16 + l15;                                      \
            aw[fi] = *(const short8*)((const char*)Bs + r * 64 +                        \
                                      ((quad ^ ((r >> 1) & 3)) << 4));                  \
        }                                                                               \
        _Pragma("unroll") for (int ti = 0; ti < 4; ++ti) {                              \
            const int r = wx * 64 + ti * 16 + l15;                                      \
            bt[ti] = *(const short8*)((const char*)As + r * 64 +                        \
                                      ((quad ^ ((r >> 1) & 3)) << 4));                  \
        }                                                                               \
        _Pragma("unroll") for (int fi = 0; fi < 4; ++fi)                                \
            _Pragma("unroll") for (int ti = 0; ti < 4; ++ti)                            \
                acc[fi][ti] = __builtin_amdgcn_mfma_f32_16x16x32_bf16(                  \
                    aw[fi], bt[ti], acc[fi][ti], 0, 0, 0);                              \
    }

// QKV projection -> Q,K bf16 [token][512]; V fp16 [token][512] (z==2)
__global__ __launch_bounds__(256) void gemm_qkv(
    const ushort_t* __restrict__ A,
    const ushort_t* __restrict__ W0, const ushort_t* __restrict__ W1,
    const ushort_t* __restrict__ W2,
    const float* __restrict__ b0, const float* __restrict__ b1,
    const float* __restrict__ b2,
    ushort_t* __restrict__ o0, ushort_t* __restrict__ o1, ushort_t* __restrict__ o2) {
    const ushort_t* W; const float* bias; ushort_t* dst;
    if (blockIdx.z == 0)      { W = W0; bias = b0; dst = o0; }
    else if (blockIdx.z == 1) { W = W1; bias = b1; dst = o1; }
    else                      { W = W2; bias = b2; dst = o2; }
    const bool as_f16 = (blockIdx.z == 2);
    GEMM_CORE(A, W)
    #pragma unroll
    for (int fi = 0; fi < 4; ++fi) {
        const int f = n0 + wy * 64 + fi * 16 + quad * 4;
        const float4 b4 = *(const float4*)&bias[f];
        #pragma unroll
        for (int ti = 0; ti < 4; ++ti) {
            const int token = m0 + wx * 64 + ti * 16 + l15;
            const float v0 = acc[fi][ti][0] + b4.x, v1 = acc[fi][ti][1] + b4.y;
            const float v2 = acc[fi][ti][2] + b4.z, v3 = acc[fi][ti][3] + b4.w;
            uint2 v;
            if (as_f16) { v.x = pkh(v0, v1);  v.y = pkh(v2, v3); }
            else        { v.x = pkbf(v0, v1); v.y = pkbf(v2, v3); }
            *(uint2*)&dst[(size_t)token * DDIM + f] = v;
        }
    }
}

// Output projection -> fp32 [token][512]
__global__ __launch_bounds__(256) void gemm_out(
    const ushort_t* __restrict__ A, const ushort_t* __restrict__ Wo,
    const float* __restrict__ bo, float* __restrict__ dst) {
    GEMM_CORE(A, Wo)
    #pragma unroll
    for (int fi = 0; fi < 4; ++fi) {
        const int f = n0 + wy * 64 + fi * 16 + quad * 4;
        const float4 b4 = *(const float4*)&bo[f];
        #pragma unroll
        for (int ti = 0; ti < 4; ++ti) {
            const int token = m0 + wx * 64 + ti * 16 + l15;
            float4 v;
            v.x = acc[fi][ti][0] + b4.x; v.y = acc[fi][ti][1] + b4.y;
            v.z = acc[fi][ti][2] + b4.z; v.w = acc[fi][ti][3] + b4.w;
            *(float4*)&dst[(size_t)token * DDIM + f] = v;
        }
    }
}

// ---------------------------------------------------------------------------
// Persistent-KV MFMA attention, 32x32 MFMA + in-register P.
// One block per (h,b) = 256 blocks. 512 threads (8 waves); wave w owns q rows
// w*64..w*64+63 as 2 q-tiles of 32. K (bf16, 64KB) + V^T (fp16, 64KB) staged
// to LDS once; zero-barrier main loop. S^T = K.Q^T via mfma_f32_32x32x16_bf16
// (C: col=q=lane&31, row=k=(reg&3)+8*(reg>>2)+4*(lane>>5)). P converted to
// fp16 in-register (cvt_pkrtz) and moved to the PV B-operand layout
// (n=q=lane&31, k=(lane>>5)*8+j) with two v_permlane32_swap_b32 per 16-k
// step. HW semantic: swap(VDST[32+i], VSRC[i]) -> for (a,b):
// a'={a.lo,b.lo}, b'={a.hi,b.hi}. Needed: word0={w0.lo,w2.lo},
// word2={w0.hi,w2.hi} -> permlane32_swap(w0,w2) gives (word0, word2);
// permlane32_swap(w1,w3) gives (word1, word3).  (Round-0 had vdst/vsrc
// reversed -> mispaired P.V -> absmax 4.9e-2.)
// No P LDS buffer, no lgkmcnt in the softmax->PV chain.
// ---------------------------------------------------------------------------
__global__ __launch_bounds__(512, 2) void attn_fused(
    const ushort_t* __restrict__ Qg, const ushort_t* __restrict__ Kg,
    const ushort_t* __restrict__ Vtg, const ushort_t* __restrict__ Tg,
    ushort_t* __restrict__ aout) {
    __shared__ ushort_t Ks[512 * 64];   // 64KB: row kj, 128B, 8x16B grans, gran g = global g^key(kj)
    __shared__ ushort_t Vs[64 * 512];   // 64KB: row d, 1024B, 64 grans, gran g = global g^key(d)

    const int tid = threadIdx.x, lane = tid & 63, wid = tid >> 6;
    const int l31 = lane & 31, hl = lane >> 5;
    const int h = blockIdx.x, b = blockIdx.y;
    const float K1 = 0.18033688f;       // 0.125 * log2(e)

    // ---- stage K + V^T (once) ----
    #pragma unroll
    for (int j = 0; j < 8; ++j) {
        const int t = wid * 8 + j;
        {   // K rows t*8 .. t*8+7 (1KB per wave-load)
            const int row = t * 8 + (lane >> 3);
            const int key = (row & 7) ^ ((row >> 3) & 7);
            const int g = (lane & 7) ^ key;
            gl_lds16(Kg + (size_t)(b * NN + row) * DDIM + h * DK + g * 8,
                     (char*)Ks + t * 1024);
        }
        {   // V^T row d = t (1KB per wave-load)
            const int key = (t & 7) ^ ((t >> 3) & 7);
            const int g = lane ^ key;
            gl_lds16(Vtg + (size_t)((b * HH + h) * DK + t) * NN + g * 8,
                     (char*)Vs + t * 1024);
        }
    }

    // ---- Q fragments (B-operand: n=q=lane&31, k=dk=(lane>>5)*8+j) ----
    short8 bq[2][4];
    #pragma unroll
    for (int qt = 0; qt < 2; ++qt) {
        const ushort_t* qp =
            Qg + (size_t)(b * NN + wid * 64 + qt * 32 + l31) * DDIM + h * DK + hl * 8;
        #pragma unroll
        for (int st = 0; st < 4; ++st) bq[qt][st] = *(const short8*)(qp + st * 16);
    }

    float lsum[2] = {0.f, 0.f};
    floatx16 O[2][2];                    // [qt][dt], C: col=q, row=d
    #pragma unroll
    for (int qt = 0; qt < 2; ++qt)
        #pragma unroll
        for (int dt = 0; dt < 2; ++dt)
            #pragma unroll
            for (int r = 0; r < 16; ++r) O[qt][dt][r] = 0.f;

    __syncthreads();   // the only barrier

    for (int kt = 0; kt < 8; ++kt) {
        // T prefetch: tv[qt][kti][g] covers k = kt*64 + kti*32 + g*8 + hl*4 + 0..3
        uint2 tv[2][2][4];
        #pragma unroll
        for (int qt = 0; qt < 2; ++qt) {
            const ushort_t* tp =
                Tg + (size_t)(b * NN + wid * 64 + qt * 32 + l31) * NN + kt * 64 + hl * 4;
            #pragma unroll
            for (int kti = 0; kti < 2; ++kti)
                #pragma unroll
                for (int g = 0; g < 4; ++g)
                    tv[qt][kti][g] = *(const uint2*)(tp + kti * 32 + g * 8);
        }

        // K fragments (A: m=k-row=lane&31(+base), k=dk=(lane>>5)*8+j), once per kt
        short8 kf[2][4];
        #pragma unroll
        for (int kti = 0; kti < 2; ++kti) {
            const int row = kt * 64 + kti * 32 + l31;
            const int key = (row & 7) ^ ((row >> 3) & 7);
            #pragma unroll
            for (int st = 0; st < 4; ++st)
                kf[kti][st] = *(const short8*)((const char*)Ks + row * 128 +
                                               (((st * 2 + hl) ^ key) << 4));
        }

        // V^T fragments (A: m=d=lane&31(+dt*32), k=(lane>>5)*8+j), once per kt
        half8 vf[2][2][2];   // [kti][dt][ks]
        #pragma unroll
        for (int dt = 0; dt < 2; ++dt) {
            const int d = dt * 32 + l31;
            const int key = (d & 7) ^ ((d >> 3) & 7);
            #pragma unroll
            for (int kti = 0; kti < 2; ++kti)
                #pragma unroll
                for (int ks = 0; ks < 2; ++ks)
                    vf[kti][dt][ks] = *(const half8*)((const char*)Vs + d * 1024 +
                        (((kt * 8 + kti * 4 + ks * 2 + hl) ^ key) << 4));
        }

        #pragma unroll
        for (int qt = 0; qt < 2; ++qt)
            #pragma unroll
            for (int kti = 0; kti < 2; ++kti) {
                // S^T tile [32k x 32q] = K.Q^T
                floatx16 S;
                #pragma unroll
                for (int r = 0; r < 16; ++r) S[r] = 0.f;
                __builtin_amdgcn_s_setprio(1);
                #pragma unroll
                for (int st = 0; st < 4; ++st)
                    S = __builtin_amdgcn_mfma_f32_32x32x16_bf16(
                        kf[kti][st], bq[qt][st], S, 0, 0, 0);
                __builtin_amdgcn_s_setprio(0);

                float ls = 0.f;
                #pragma unroll
                for (int ks = 0; ks < 2; ++ks) {       // 16-k PV step
                    float pp[8];
                    #pragma unroll
                    for (int gg = 0; gg < 2; ++gg) {
                        const uint2 tg = tv[qt][kti][ks * 2 + gg];
                        const float t0 = h2f((ushort_t)tg.x);
                        const float t1 = h2f((ushort_t)(tg.x >> 16));
                        const float t2 = h2f((ushort_t)tg.y);
                        const float t3 = h2f((ushort_t)(tg.y >> 16));
                        const int sb = ks * 8 + gg * 4;
                        pp[gg * 4 + 0] = exp2f(S[sb + 0] * K1 + t0);
                        pp[gg * 4 + 1] = exp2f(S[sb + 1] * K1 + t1);
                        pp[gg * 4 + 2] = exp2f(S[sb + 2] * K1 + t2);
                        pp[gg * 4 + 3] = exp2f(S[sb + 3] * K1 + t3);
                        ls += (pp[gg * 4 + 0] + pp[gg * 4 + 1]) +
                              (pp[gg * 4 + 2] + pp[gg * 4 + 3]);
                    }
                    // pack own 8 P vals to fp16, half-exchange to B layout:
                    // lane's pp[gg*4+r] holds k_off = 8*gg + 4*hl + r.
                    // B needs k = 8*hl + j. swap(w0,w2) -> (word0, word2);
                    // swap(w1,w3) -> (word1, word3).
                    uint_t w0 = pkh(pp[0], pp[1]);   // own pk01
                    uint_t w1 = pkh(pp[2], pp[3]);   // own pk23
                    uint_t w2 = pkh(pp[4], pp[5]);   // own pk45
                    uint_t w3 = pkh(pp[6], pp[7]);   // own pk67
                    auto r02 = __builtin_amdgcn_permlane32_swap(w0, w2, false, false);
                    auto r13 = __builtin_amdgcn_permlane32_swap(w1, w3, false, false);
                    uint4 uu;
                    uu.x = r02[0];   // word0 = {w0.lo, w2.lo}
                    uu.y = r13[0];   // word1 = {w1.lo, w3.lo}
                    uu.z = r02[1];   // word2 = {w0.hi, w2.hi}
                    uu.w = r13[1];   // word3 = {w1.hi, w3.hi}
                    const half8 bp = __builtin_bit_cast(half8, uu);

                    __builtin_amdgcn_s_setprio(1);
                    #pragma unroll
                    for (int dt = 0; dt < 2; ++dt)
                        O[qt][dt] = __builtin_amdgcn_mfma_f32_32x32x16_f16(
                            vf[kti][dt][ks], bp, O[qt][dt], 0, 0, 0);
                    __builtin_amdgcn_s_setprio(0);
                }
                lsum[qt] += ls;
            }
    }

    // ---- epilogue: reduce l over lane halves, normalize, write bf16 ----
    #pragma unroll
    for (int qt = 0; qt < 2; ++qt) {
        float l = lsum[qt];
        l += __shfl_xor(l, 32);
        const float inv = 1.0f / l;
        const size_t orow =
            (size_t)(b * NN + wid * 64 + qt * 32 + l31) * DDIM + h * DK;
        #pragma unroll
        for (int dt = 0; dt < 2; ++dt)
            #pragma unroll
            for (int g = 0; g < 4; ++g) {
                const int d = dt * 32 + g * 8 + hl * 4;
                uint2 ov;
                ov.x = pkbf(O[qt][dt][g * 4 + 0] * inv, O[qt][dt][g * 4 + 1] * inv);
                ov.y = pkbf(O[qt][dt][g * 4 + 2] * inv, O[qt][dt][g * 4 + 3] * inv);
                *(uint2*)&aout[orow + d] = ov;
            }
    }
}

extern "C" void kernel_launch(void* const* d_in, const int* in_sizes, int n_in,
                              void* d_out, int out_size, void* d_ws, size_t ws_size,
                              hipStream_t stream) {
    const float* x    = (const float*)d_in[0];
    const float* dist = (const float*)d_in[1];
    const float* Wq   = (const float*)d_in[2];
    const float* bq   = (const float*)d_in[3];
    const float* Wk   = (const float*)d_in[4];
    const float* bk   = (const float*)d_in[5];
    const float* Wv   = (const float*)d_in[6];
    const float* bv   = (const float*)d_in[7];
    const float* Wo   = (const float*)d_in[8];
    const float* bo   = (const float*)d_in[9];
    const float* dw   = (const float*)d_in[10];
    float* out = (float*)d_out;

    const size_t NELT = (size_t)BB * NN * DDIM;   // 8388608
    ushort_t* xb  = (ushort_t*)d_ws;              // x bf16; aliased by ab later
    ushort_t* wqb = xb + NELT;
    ushort_t* wkb = wqb + DDIM * DDIM;
    ushort_t* wvb = wkb + DDIM * DDIM;
    ushort_t* wob = wvb + DDIM * DDIM;
    ushort_t* qb  = wob + DDIM * DDIM;
    ushort_t* kb  = qb + NELT;
    ushort_t* vb  = kb + NELT;                    // fp16
    ushort_t* vt  = vb + NELT;                    // fp16, transposed
    ushort_t* Tm  = vt + NELT;                    // fp16 bias matrix
    ushort_t* ab  = xb;                           // alias: xb dead after gemm_qkv

    cvt_bf16<<<4096, 256, 0, stream>>>(x, xb, (int)(NELT / 8));
    cvt_w4<<<dim3(128, 4), 256, 0, stream>>>(Wq, Wk, Wv, Wo, wqb, wkb, wvb, wob);
    bias_half<<<4096, 256, 0, stream>>>(dist, dw, Tm, (int)(NELT / 8));

    gemm_qkv<<<dim3(128, 4, 3), 256, 0, stream>>>(xb, wqb, wkb, wvb, bq, bk, bv,
                                                  qb, kb, vb);
    transp_v<<<dim3(8, 256), 256, 0, stream>>>(vb, vt);
    attn_fused<<<dim3(HH, BB), 512, 0, stream>>>(qb, kb, vt, Tm, ab);
    gemm_out<<<dim3(128, 4), 256, 0, stream>>>(ab, wob, bo, out);
}

// Round 3
// 238.649 us; speedup vs baseline: 1.1364x; 1.1364x over previous
//
#include <hip/hip_runtime.h>
#include <hip/hip_fp16.h>
#include <math.h>
#include <stdint.h>

#define BB 32
#define NN 512
#define DDIM 512
#define HH 8
#define DK 64

typedef __attribute__((ext_vector_type(8))) short short8;
typedef __attribute__((ext_vector_type(8))) _Float16 half8;
typedef __attribute__((ext_vector_type(2))) _Float16 half2v;
typedef __attribute__((ext_vector_type(4))) float floatx4;
typedef __attribute__((ext_vector_type(16))) float floatx16;
typedef unsigned short ushort_t;
typedef unsigned int uint_t;

// async global->LDS, 16B/lane; LDS dest = wave-uniform base + lane*16
__device__ __forceinline__ void gl_lds16(const void* g, void* l) {
    __builtin_amdgcn_global_load_lds(
        (const __attribute__((address_space(1))) uint_t*)g,
        (__attribute__((address_space(3))) uint_t*)l,
        16, 0, 0);
}

__device__ __forceinline__ ushort_t f2bf(float f) {  // RNE fp32->bf16
    uint_t u = __builtin_bit_cast(uint_t, f);
    u += 0x7fff + ((u >> 16) & 1);
    return (ushort_t)(u >> 16);
}

__device__ __forceinline__ uint_t pkbf(float a, float b) {
    return (uint_t)f2bf(a) | ((uint_t)f2bf(b) << 16);
}

__device__ __forceinline__ uint_t pkh(float a, float b) {  // 2xf32 -> f16x2 (RTZ, 1 inst)
    return __builtin_bit_cast(uint_t, __builtin_amdgcn_cvt_pkrtz(a, b));
}

__device__ __forceinline__ float h2f(ushort_t u) {
    return __half2float(__ushort_as_half(u));
}

// ---------------------------------------------------------------------------
// prep kernels
// ---------------------------------------------------------------------------
__global__ __launch_bounds__(256) void cvt_bf16(const float* __restrict__ s,
                                                ushort_t* __restrict__ d, int n8) {
    const int i = blockIdx.x * 256 + threadIdx.x;
    if (i >= n8) return;
    const float4 a = ((const float4*)s)[i * 2 + 0];
    const float4 b = ((const float4*)s)[i * 2 + 1];
    uint4 o;
    o.x = pkbf(a.x, a.y); o.y = pkbf(a.z, a.w);
    o.z = pkbf(b.x, b.y); o.w = pkbf(b.z, b.w);
    *(uint4*)(d + i * 8) = o;
}

__global__ __launch_bounds__(256) void cvt_w4(
    const float* __restrict__ w0, const float* __restrict__ w1,
    const float* __restrict__ w2, const float* __restrict__ w3,
    ushort_t* __restrict__ o0, ushort_t* __restrict__ o1,
    ushort_t* __restrict__ o2, ushort_t* __restrict__ o3) {
    const float* s; ushort_t* d;
    if (blockIdx.y == 0)      { s = w0; d = o0; }
    else if (blockIdx.y == 1) { s = w1; d = o1; }
    else if (blockIdx.y == 2) { s = w2; d = o2; }
    else                      { s = w3; d = o3; }
    const int i = blockIdx.x * 256 + threadIdx.x;
    const float4 a = ((const float4*)s)[i * 2 + 0];
    const float4 b = ((const float4*)s)[i * 2 + 1];
    uint4 o;
    o.x = pkbf(a.x, a.y); o.y = pkbf(a.z, a.w);
    o.z = pkbf(b.x, b.y); o.w = pkbf(b.z, b.w);
    *(uint4*)(d + i * 8) = o;
}

// distance -> fp16 T[bin] = (dw[bin]-3)*log2e  (constant-max softmax, base-2)
__global__ __launch_bounds__(256) void bias_half(const float* __restrict__ dist,
                                                 const float* __restrict__ dw,
                                                 ushort_t* __restrict__ T, int n8) {
    __shared__ float dws[21];
    if (threadIdx.x < 21) dws[threadIdx.x] = (dw[threadIdx.x] - 3.0f) * 1.44269504f;
    __syncthreads();
    const int i = blockIdx.x * 256 + threadIdx.x;
    if (i >= n8) return;
    float dv[8];
    { const float4 a = ((const float4*)dist)[i * 2 + 0];
      const float4 b = ((const float4*)dist)[i * 2 + 1];
      dv[0]=a.x; dv[1]=a.y; dv[2]=a.z; dv[3]=a.w;
      dv[4]=b.x; dv[5]=b.y; dv[6]=b.z; dv[7]=b.w; }
    ushort_t h[8];
    #pragma unroll
    for (int j = 0; j < 8; ++j) {
        int bin = (int)(dv[j] / 5.0f);
        bin = bin < 0 ? 0 : (bin > 20 ? 20 : bin);
        h[j] = __half_as_ushort(__float2half(dws[bin]));
    }
    uint4 o;
    o.x = (uint_t)h[0] | ((uint_t)h[1] << 16);
    o.y = (uint_t)h[2] | ((uint_t)h[3] << 16);
    o.z = (uint_t)h[4] | ((uint_t)h[5] << 16);
    o.w = (uint_t)h[6] | ((uint_t)h[7] << 16);
    *(uint4*)(T + i * 8) = o;
}

// V (fp16) [b][q][h*64+d] -> Vt [(b*8+h)*64+d][512]  (dtype-opaque transpose)
__global__ __launch_bounds__(256) void transp_v(const ushort_t* __restrict__ V,
                                                ushort_t* __restrict__ Vt) {
    __shared__ ushort_t T[64][72];
    const int tid = threadIdx.x;
    const int q0 = blockIdx.x * 64;
    const int bh = blockIdx.y, b = bh >> 3, h = bh & 7;
    #pragma unroll
    for (int rnd = 0; rnd < 2; ++rnd) {
        const int idx = rnd * 256 + tid;
        const int row = idx >> 3, c8 = (idx & 7) * 8;
        const uint4 v = *(const uint4*)&V[((size_t)(b * NN + q0 + row)) * DDIM + h * DK + c8];
        ushort_t* t = &T[row][c8];
        t[0] = (ushort_t)v.x; t[1] = (ushort_t)(v.x >> 16);
        t[2] = (ushort_t)v.y; t[3] = (ushort_t)(v.y >> 16);
        t[4] = (ushort_t)v.z; t[5] = (ushort_t)(v.z >> 16);
        t[6] = (ushort_t)v.w; t[7] = (ushort_t)(v.w >> 16);
    }
    __syncthreads();
    #pragma unroll
    for (int rnd = 0; rnd < 2; ++rnd) {
        const int idx = rnd * 256 + tid;
        const int d = idx >> 3, q8 = (idx & 7) * 8;
        uint4 o;
        o.x = (uint_t)T[q8 + 0][d] | ((uint_t)T[q8 + 1][d] << 16);
        o.y = (uint_t)T[q8 + 2][d] | ((uint_t)T[q8 + 3][d] << 16);
        o.z = (uint_t)T[q8 + 4][d] | ((uint_t)T[q8 + 5][d] << 16);
        o.w = (uint_t)T[q8 + 6][d] | ((uint_t)T[q8 + 7][d] << 16);
        *(uint4*)&Vt[((size_t)(bh * DK + d)) * NN + q0 + q8] = o;
    }
}

// ---------------------------------------------------------------------------
// GEMM core: D[feat][token] = W x A^T. 128x128 tile, BK=32, global_load_lds,
// XOR chunk swizzle.
// ---------------------------------------------------------------------------
#define GEMM_CORE(Aptr, Wptr)                                                           \
    __shared__ ushort_t As[128 * 32];                                                   \
    __shared__ ushort_t Bs[128 * 32];                                                   \
    const int tid = threadIdx.x;                                                        \
    const int lane = tid & 63, wid = tid >> 6;                                          \
    const int quad = lane >> 4, l15 = lane & 15;                                        \
    const int m0 = blockIdx.x * 128, n0 = blockIdx.y * 128;                             \
    const int wy = wid >> 1, wx = wid & 1;                                              \
    floatx4 acc[4][4];                                                                  \
    _Pragma("unroll") for (int i = 0; i < 4; ++i)                                       \
        _Pragma("unroll") for (int j = 0; j < 4; ++j)                                   \
            _Pragma("unroll") for (int r = 0; r < 4; ++r) acc[i][j][r] = 0.f;           \
    for (int k0 = 0; k0 < DDIM; k0 += 32) {                                             \
        __syncthreads();                                                                \
        _Pragma("unroll") for (int j = 0; j < 4; ++j) {                                 \
            const int t = wid * 4 + j;                                                  \
            const int rowi = ((t & 7) << 4) + (lane >> 2);                              \
            const int cd = (lane & 3) ^ ((rowi >> 1) & 3);                              \
            if (t < 8)                                                                  \
                gl_lds16(Aptr + (size_t)(m0 + rowi) * DDIM + k0 + cd * 8,               \
                         (char*)As + ((t & 7) << 10));                                  \
            else                                                                        \
                gl_lds16(Wptr + (size_t)(n0 + rowi) * DDIM + k0 + cd * 8,               \
                         (char*)Bs + ((t & 7) << 10));                                  \
        }                                                                               \
        __syncthreads();                                                                \
        short8 aw[4], bt[4];                                                            \
        _Pragma("unroll") for (int fi = 0; fi < 4; ++fi) {                              \
            const int r = wy * 64 + fi * 16 + l15;                                      \
            aw[fi] = *(const short8*)((const char*)Bs + r * 64 +                        \
                                      ((quad ^ ((r >> 1) & 3)) << 4));                  \
        }                                                                               \
        _Pragma("unroll") for (int ti = 0; ti < 4; ++ti) {                              \
            const int r = wx * 64 + ti * 16 + l15;                                      \
            bt[ti] = *(const short8*)((const char*)As + r * 64 +                        \
                                      ((quad ^ ((r >> 1) & 3)) << 4));                  \
        }                                                                               \
        _Pragma("unroll") for (int fi = 0; fi < 4; ++fi)                                \
            _Pragma("unroll") for (int ti = 0; ti < 4; ++ti)                            \
                acc[fi][ti] = __builtin_amdgcn_mfma_f32_16x16x32_bf16(                  \
                    aw[fi], bt[ti], acc[fi][ti], 0, 0, 0);                              \
    }

// QKV projection -> Q,K bf16 [token][512]; V fp16 [token][512] (z==2)
__global__ __launch_bounds__(256) void gemm_qkv(
    const ushort_t* __restrict__ A,
    const ushort_t* __restrict__ W0, const ushort_t* __restrict__ W1,
    const ushort_t* __restrict__ W2,
    const float* __restrict__ b0, const float* __restrict__ b1,
    const float* __restrict__ b2,
    ushort_t* __restrict__ o0, ushort_t* __restrict__ o1, ushort_t* __restrict__ o2) {
    const ushort_t* W; const float* bias; ushort_t* dst;
    if (blockIdx.z == 0)      { W = W0; bias = b0; dst = o0; }
    else if (blockIdx.z == 1) { W = W1; bias = b1; dst = o1; }
    else                      { W = W2; bias = b2; dst = o2; }
    const bool as_f16 = (blockIdx.z == 2);
    GEMM_CORE(A, W)
    #pragma unroll
    for (int fi = 0; fi < 4; ++fi) {
        const int f = n0 + wy * 64 + fi * 16 + quad * 4;
        const float4 b4 = *(const float4*)&bias[f];
        #pragma unroll
        for (int ti = 0; ti < 4; ++ti) {
            const int token = m0 + wx * 64 + ti * 16 + l15;
            const float v0 = acc[fi][ti][0] + b4.x, v1 = acc[fi][ti][1] + b4.y;
            const float v2 = acc[fi][ti][2] + b4.z, v3 = acc[fi][ti][3] + b4.w;
            uint2 v;
            if (as_f16) { v.x = pkh(v0, v1);  v.y = pkh(v2, v3); }
            else        { v.x = pkbf(v0, v1); v.y = pkbf(v2, v3); }
            *(uint2*)&dst[(size_t)token * DDIM + f] = v;
        }
    }
}

// Output projection -> fp32 [token][512]
__global__ __launch_bounds__(256) void gemm_out(
    const ushort_t* __restrict__ A, const ushort_t* __restrict__ Wo,
    const float* __restrict__ bo, float* __restrict__ dst) {
    GEMM_CORE(A, Wo)
    #pragma unroll
    for (int fi = 0; fi < 4; ++fi) {
        const int f = n0 + wy * 64 + fi * 16 + quad * 4;
        const float4 b4 = *(const float4*)&bo[f];
        #pragma unroll
        for (int ti = 0; ti < 4; ++ti) {
            const int token = m0 + wx * 64 + ti * 16 + l15;
            float4 v;
            v.x = acc[fi][ti][0] + b4.x; v.y = acc[fi][ti][1] + b4.y;
            v.z = acc[fi][ti][2] + b4.z; v.w = acc[fi][ti][3] + b4.w;
            *(float4*)&dst[(size_t)token * DDIM + f] = v;
        }
    }
}

// ---------------------------------------------------------------------------
// Persistent-KV MFMA attention, 32x32 MFMA + in-register P.
// Round-2 changes (register pressure only; math identical to round 1):
//  * __launch_bounds__(512) + amdgpu_waves_per_eu(2,2): LDS (128KB) already
//    caps at 1 block/CU = 2 waves/SIMD, so the VGPR budget at that occupancy
//    is 256/wave. Round 1's (512,2) allocated only 128 VGPR -> ~220-reg live
//    set spilled to scratch (evidence: FETCH +23MB, WRITE +12MB with
//    identical program data; MFMA/VALU busy-time unchanged; +35us stall).
//  * kti-outer / qt-inner loop: only one kti's kf/vf live at a time (-32 regs).
// P path: S^T = K.Q^T via mfma_f32_32x32x16_bf16; P packed fp16 in-register
// (cvt_pkrtz) + permlane32_swap(w0,w2)/(w1,w3) -> PV B-operand; no P LDS.
// ---------------------------------------------------------------------------
__global__ __launch_bounds__(512)
__attribute__((amdgpu_waves_per_eu(2, 2)))
void attn_fused(
    const ushort_t* __restrict__ Qg, const ushort_t* __restrict__ Kg,
    const ushort_t* __restrict__ Vtg, const ushort_t* __restrict__ Tg,
    ushort_t* __restrict__ aout) {
    __shared__ ushort_t Ks[512 * 64];   // 64KB: row kj, 128B, 8x16B grans, gran g = global g^key(kj)
    __shared__ ushort_t Vs[64 * 512];   // 64KB: row d, 1024B, 64 grans, gran g = global g^key(d)

    const int tid = threadIdx.x, lane = tid & 63, wid = tid >> 6;
    const int l31 = lane & 31, hl = lane >> 5;
    const int h = blockIdx.x, b = blockIdx.y;
    const float K1 = 0.18033688f;       // 0.125 * log2(e)

    // ---- stage K + V^T (once) ----
    #pragma unroll
    for (int j = 0; j < 8; ++j) {
        const int t = wid * 8 + j;
        {   // K rows t*8 .. t*8+7 (1KB per wave-load)
            const int row = t * 8 + (lane >> 3);
            const int key = (row & 7) ^ ((row >> 3) & 7);
            const int g = (lane & 7) ^ key;
            gl_lds16(Kg + (size_t)(b * NN + row) * DDIM + h * DK + g * 8,
                     (char*)Ks + t * 1024);
        }
        {   // V^T row d = t (1KB per wave-load)
            const int key = (t & 7) ^ ((t >> 3) & 7);
            const int g = lane ^ key;
            gl_lds16(Vtg + (size_t)((b * HH + h) * DK + t) * NN + g * 8,
                     (char*)Vs + t * 1024);
        }
    }

    // ---- Q fragments (B-operand: n=q=lane&31, k=dk=(lane>>5)*8+j) ----
    short8 bq[2][4];
    #pragma unroll
    for (int qt = 0; qt < 2; ++qt) {
        const ushort_t* qp =
            Qg + (size_t)(b * NN + wid * 64 + qt * 32 + l31) * DDIM + h * DK + hl * 8;
        #pragma unroll
        for (int st = 0; st < 4; ++st) bq[qt][st] = *(const short8*)(qp + st * 16);
    }

    float lsum[2] = {0.f, 0.f};
    floatx16 O[2][2];                    // [qt][dt], C: col=q, row=d
    #pragma unroll
    for (int qt = 0; qt < 2; ++qt)
        #pragma unroll
        for (int dt = 0; dt < 2; ++dt)
            #pragma unroll
            for (int r = 0; r < 16; ++r) O[qt][dt][r] = 0.f;

    __syncthreads();   // the only barrier

    for (int kt = 0; kt < 8; ++kt) {
        // T prefetch: tv[qt][kti][g] covers k = kt*64 + kti*32 + g*8 + hl*4 + 0..3
        uint2 tv[2][2][4];
        #pragma unroll
        for (int qt = 0; qt < 2; ++qt) {
            const ushort_t* tp =
                Tg + (size_t)(b * NN + wid * 64 + qt * 32 + l31) * NN + kt * 64 + hl * 4;
            #pragma unroll
            for (int kti = 0; kti < 2; ++kti)
                #pragma unroll
                for (int g = 0; g < 4; ++g)
                    tv[qt][kti][g] = *(const uint2*)(tp + kti * 32 + g * 8);
        }

        #pragma unroll
        for (int kti = 0; kti < 2; ++kti) {
            // K fragments (A: m=k-row=lane&31(+base), k=dk=(lane>>5)*8+j)
            short8 kf[4];
            {
                const int row = kt * 64 + kti * 32 + l31;
                const int key = (row & 7) ^ ((row >> 3) & 7);
                #pragma unroll
                for (int st = 0; st < 4; ++st)
                    kf[st] = *(const short8*)((const char*)Ks + row * 128 +
                                              (((st * 2 + hl) ^ key) << 4));
            }
            // V^T fragments (A: m=d=lane&31(+dt*32), k=(lane>>5)*8+j)
            half8 vf[2][2];   // [dt][ks]
            #pragma unroll
            for (int dt = 0; dt < 2; ++dt) {
                const int d = dt * 32 + l31;
                const int key = (d & 7) ^ ((d >> 3) & 7);
                #pragma unroll
                for (int ks = 0; ks < 2; ++ks)
                    vf[dt][ks] = *(const half8*)((const char*)Vs + d * 1024 +
                        (((kt * 8 + kti * 4 + ks * 2 + hl) ^ key) << 4));
            }

            #pragma unroll
            for (int qt = 0; qt < 2; ++qt) {
                // S^T tile [32k x 32q] = K.Q^T
                floatx16 S;
                #pragma unroll
                for (int r = 0; r < 16; ++r) S[r] = 0.f;
                __builtin_amdgcn_s_setprio(1);
                #pragma unroll
                for (int st = 0; st < 4; ++st)
                    S = __builtin_amdgcn_mfma_f32_32x32x16_bf16(
                        kf[st], bq[qt][st], S, 0, 0, 0);
                __builtin_amdgcn_s_setprio(0);

                float ls = 0.f;
                #pragma unroll
                for (int ks = 0; ks < 2; ++ks) {       // 16-k PV step
                    float pp[8];
                    #pragma unroll
                    for (int gg = 0; gg < 2; ++gg) {
                        const uint2 tg = tv[qt][kti][ks * 2 + gg];
                        const float t0 = h2f((ushort_t)tg.x);
                        const float t1 = h2f((ushort_t)(tg.x >> 16));
                        const float t2 = h2f((ushort_t)tg.y);
                        const float t3 = h2f((ushort_t)(tg.y >> 16));
                        const int sb = ks * 8 + gg * 4;
                        pp[gg * 4 + 0] = exp2f(S[sb + 0] * K1 + t0);
                        pp[gg * 4 + 1] = exp2f(S[sb + 1] * K1 + t1);
                        pp[gg * 4 + 2] = exp2f(S[sb + 2] * K1 + t2);
                        pp[gg * 4 + 3] = exp2f(S[sb + 3] * K1 + t3);
                        ls += (pp[gg * 4 + 0] + pp[gg * 4 + 1]) +
                              (pp[gg * 4 + 2] + pp[gg * 4 + 3]);
                    }
                    // pack own 8 P vals to fp16, half-exchange to B layout:
                    // lane's pp[gg*4+r] holds k_off = 8*gg + 4*hl + r.
                    // B needs k = 8*hl + j. swap(w0,w2) -> (word0, word2);
                    // swap(w1,w3) -> (word1, word3).
                    uint_t w0 = pkh(pp[0], pp[1]);   // own pk01
                    uint_t w1 = pkh(pp[2], pp[3]);   // own pk23
                    uint_t w2 = pkh(pp[4], pp[5]);   // own pk45
                    uint_t w3 = pkh(pp[6], pp[7]);   // own pk67
                    auto r02 = __builtin_amdgcn_permlane32_swap(w0, w2, false, false);
                    auto r13 = __builtin_amdgcn_permlane32_swap(w1, w3, false, false);
                    uint4 uu;
                    uu.x = r02[0];   // word0 = {w0.lo, w2.lo}
                    uu.y = r13[0];   // word1 = {w1.lo, w3.lo}
                    uu.z = r02[1];   // word2 = {w0.hi, w2.hi}
                    uu.w = r13[1];   // word3 = {w1.hi, w3.hi}
                    const half8 bp = __builtin_bit_cast(half8, uu);

                    __builtin_amdgcn_s_setprio(1);
                    #pragma unroll
                    for (int dt = 0; dt < 2; ++dt)
                        O[qt][dt] = __builtin_amdgcn_mfma_f32_32x32x16_f16(
                            vf[dt][ks], bp, O[qt][dt], 0, 0, 0);
                    __builtin_amdgcn_s_setprio(0);
                }
                lsum[qt] += ls;
            }
        }
    }

    // ---- epilogue: reduce l over lane halves, normalize, write bf16 ----
    #pragma unroll
    for (int qt = 0; qt < 2; ++qt) {
        float l = lsum[qt];
        l += __shfl_xor(l, 32);
        const float inv = 1.0f / l;
        const size_t orow =
            (size_t)(b * NN + wid * 64 + qt * 32 + l31) * DDIM + h * DK;
        #pragma unroll
        for (int dt = 0; dt < 2; ++dt)
            #pragma unroll
            for (int g = 0; g < 4; ++g) {
                const int d = dt * 32 + g * 8 + hl * 4;
                uint2 ov;
                ov.x = pkbf(O[qt][dt][g * 4 + 0] * inv, O[qt][dt][g * 4 + 1] * inv);
                ov.y = pkbf(O[qt][dt][g * 4 + 2] * inv, O[qt][dt][g * 4 + 3] * inv);
                *(uint2*)&aout[orow + d] = ov;
            }
    }
}

extern "C" void kernel_launch(void* const* d_in, const int* in_sizes, int n_in,
                              void* d_out, int out_size, void* d_ws, size_t ws_size,
                              hipStream_t stream) {
    const float* x    = (const float*)d_in[0];
    const float* dist = (const float*)d_in[1];
    const float* Wq   = (const float*)d_in[2];
    const float* bq   = (const float*)d_in[3];
    const float* Wk   = (const float*)d_in[4];
    const float* bk   = (const float*)d_in[5];
    const float* Wv   = (const float*)d_in[6];
    const float* bv   = (const float*)d_in[7];
    const float* Wo   = (const float*)d_in[8];
    const float* bo   = (const float*)d_in[9];
    const float* dw   = (const float*)d_in[10];
    float* out = (float*)d_out;

    const size_t NELT = (size_t)BB * NN * DDIM;   // 8388608
    ushort_t* xb  = (ushort_t*)d_ws;              // x bf16; aliased by ab later
    ushort_t* wqb = xb + NELT;
    ushort_t* wkb = wqb + DDIM * DDIM;
    ushort_t* wvb = wkb + DDIM * DDIM;
    ushort_t* wob = wvb + DDIM * DDIM;
    ushort_t* qb  = wob + DDIM * DDIM;
    ushort_t* kb  = qb + NELT;
    ushort_t* vb  = kb + NELT;                    // fp16
    ushort_t* vt  = vb + NELT;                    // fp16, transposed
    ushort_t* Tm  = vt + NELT;                    // fp16 bias matrix
    ushort_t* ab  = xb;                           // alias: xb dead after gemm_qkv

    cvt_bf16<<<4096, 256, 0, stream>>>(x, xb, (int)(NELT / 8));
    cvt_w4<<<dim3(128, 4), 256, 0, stream>>>(Wq, Wk, Wv, Wo, wqb, wkb, wvb, wob);
    bias_half<<<4096, 256, 0, stream>>>(dist, dw, Tm, (int)(NELT / 8));

    gemm_qkv<<<dim3(128, 4, 3), 256, 0, stream>>>(xb, wqb, wkb, wvb, bq, bk, bv,
                                                  qb, kb, vb);
    transp_v<<<dim3(8, 256), 256, 0, stream>>>(vb, vt);
    attn_fused<<<dim3(HH, BB), 512, 0, stream>>>(qb, kb, vt, Tm, ab);
    gemm_out<<<dim3(128, 4), 256, 0, stream>>>(ab, wob, bo, out);
}

// Round 4
// 238.153 us; speedup vs baseline: 1.1387x; 1.0021x over previous
//
#include <hip/hip_runtime.h>
#include <hip/hip_fp16.h>
#include <math.h>
#include <stdint.h>

#define BB 32
#define NN 512
#define DDIM 512
#define HH 8
#define DK 64

typedef __attribute__((ext_vector_type(8))) short short8;
typedef __attribute__((ext_vector_type(8))) _Float16 half8;
typedef __attribute__((ext_vector_type(2))) _Float16 half2v;
typedef __attribute__((ext_vector_type(4))) float floatx4;
typedef __attribute__((ext_vector_type(16))) float floatx16;
typedef unsigned short ushort_t;
typedef unsigned int uint_t;

// async global->LDS, 16B/lane; LDS dest = wave-uniform base + lane*16
__device__ __forceinline__ void gl_lds16(const void* g, void* l) {
    __builtin_amdgcn_global_load_lds(
        (const __attribute__((address_space(1))) uint_t*)g,
        (__attribute__((address_space(3))) uint_t*)l,
        16, 0, 0);
}

__device__ __forceinline__ ushort_t f2bf(float f) {  // RNE fp32->bf16
    uint_t u = __builtin_bit_cast(uint_t, f);
    u += 0x7fff + ((u >> 16) & 1);
    return (ushort_t)(u >> 16);
}

__device__ __forceinline__ uint_t pkbf(float a, float b) {
    return (uint_t)f2bf(a) | ((uint_t)f2bf(b) << 16);
}

__device__ __forceinline__ uint_t pkh(float a, float b) {  // 2xf32 -> f16x2 (RTZ, 1 inst)
    return __builtin_bit_cast(uint_t, __builtin_amdgcn_cvt_pkrtz(a, b));
}

__device__ __forceinline__ float h2f(ushort_t u) {
    return __half2float(__ushort_as_half(u));
}

// ---------------------------------------------------------------------------
// prep kernels
// ---------------------------------------------------------------------------
__global__ __launch_bounds__(256) void cvt_bf16(const float* __restrict__ s,
                                                ushort_t* __restrict__ d, int n8) {
    const int i = blockIdx.x * 256 + threadIdx.x;
    if (i >= n8) return;
    const float4 a = ((const float4*)s)[i * 2 + 0];
    const float4 b = ((const float4*)s)[i * 2 + 1];
    uint4 o;
    o.x = pkbf(a.x, a.y); o.y = pkbf(a.z, a.w);
    o.z = pkbf(b.x, b.y); o.w = pkbf(b.z, b.w);
    *(uint4*)(d + i * 8) = o;
}

__global__ __launch_bounds__(256) void cvt_w4(
    const float* __restrict__ w0, const float* __restrict__ w1,
    const float* __restrict__ w2, const float* __restrict__ w3,
    ushort_t* __restrict__ o0, ushort_t* __restrict__ o1,
    ushort_t* __restrict__ o2, ushort_t* __restrict__ o3) {
    const float* s; ushort_t* d;
    if (blockIdx.y == 0)      { s = w0; d = o0; }
    else if (blockIdx.y == 1) { s = w1; d = o1; }
    else if (blockIdx.y == 2) { s = w2; d = o2; }
    else                      { s = w3; d = o3; }
    const int i = blockIdx.x * 256 + threadIdx.x;
    const float4 a = ((const float4*)s)[i * 2 + 0];
    const float4 b = ((const float4*)s)[i * 2 + 1];
    uint4 o;
    o.x = pkbf(a.x, a.y); o.y = pkbf(a.z, a.w);
    o.z = pkbf(b.x, b.y); o.w = pkbf(b.z, b.w);
    *(uint4*)(d + i * 8) = o;
}

// distance -> fp16 T[bin] = (dw[bin]-3)*log2e  (constant-max softmax, base-2)
__global__ __launch_bounds__(256) void bias_half(const float* __restrict__ dist,
                                                 const float* __restrict__ dw,
                                                 ushort_t* __restrict__ T, int n8) {
    __shared__ float dws[21];
    if (threadIdx.x < 21) dws[threadIdx.x] = (dw[threadIdx.x] - 3.0f) * 1.44269504f;
    __syncthreads();
    const int i = blockIdx.x * 256 + threadIdx.x;
    if (i >= n8) return;
    float dv[8];
    { const float4 a = ((const float4*)dist)[i * 2 + 0];
      const float4 b = ((const float4*)dist)[i * 2 + 1];
      dv[0]=a.x; dv[1]=a.y; dv[2]=a.z; dv[3]=a.w;
      dv[4]=b.x; dv[5]=b.y; dv[6]=b.z; dv[7]=b.w; }
    ushort_t h[8];
    #pragma unroll
    for (int j = 0; j < 8; ++j) {
        int bin = (int)(dv[j] / 5.0f);
        bin = bin < 0 ? 0 : (bin > 20 ? 20 : bin);
        h[j] = __half_as_ushort(__float2half(dws[bin]));
    }
    uint4 o;
    o.x = (uint_t)h[0] | ((uint_t)h[1] << 16);
    o.y = (uint_t)h[2] | ((uint_t)h[3] << 16);
    o.z = (uint_t)h[4] | ((uint_t)h[5] << 16);
    o.w = (uint_t)h[6] | ((uint_t)h[7] << 16);
    *(uint4*)(T + i * 8) = o;
}

// V (fp16) [b][q][h*64+d] -> Vt [(b*8+h)*64+d][512]  (dtype-opaque transpose)
__global__ __launch_bounds__(256) void transp_v(const ushort_t* __restrict__ V,
                                                ushort_t* __restrict__ Vt) {
    __shared__ ushort_t T[64][72];
    const int tid = threadIdx.x;
    const int q0 = blockIdx.x * 64;
    const int bh = blockIdx.y, b = bh >> 3, h = bh & 7;
    #pragma unroll
    for (int rnd = 0; rnd < 2; ++rnd) {
        const int idx = rnd * 256 + tid;
        const int row = idx >> 3, c8 = (idx & 7) * 8;
        const uint4 v = *(const uint4*)&V[((size_t)(b * NN + q0 + row)) * DDIM + h * DK + c8];
        ushort_t* t = &T[row][c8];
        t[0] = (ushort_t)v.x; t[1] = (ushort_t)(v.x >> 16);
        t[2] = (ushort_t)v.y; t[3] = (ushort_t)(v.y >> 16);
        t[4] = (ushort_t)v.z; t[5] = (ushort_t)(v.z >> 16);
        t[6] = (ushort_t)v.w; t[7] = (ushort_t)(v.w >> 16);
    }
    __syncthreads();
    #pragma unroll
    for (int rnd = 0; rnd < 2; ++rnd) {
        const int idx = rnd * 256 + tid;
        const int d = idx >> 3, q8 = (idx & 7) * 8;
        uint4 o;
        o.x = (uint_t)T[q8 + 0][d] | ((uint_t)T[q8 + 1][d] << 16);
        o.y = (uint_t)T[q8 + 2][d] | ((uint_t)T[q8 + 3][d] << 16);
        o.z = (uint_t)T[q8 + 4][d] | ((uint_t)T[q8 + 5][d] << 16);
        o.w = (uint_t)T[q8 + 6][d] | ((uint_t)T[q8 + 7][d] << 16);
        *(uint4*)&Vt[((size_t)(bh * DK + d)) * NN + q0 + q8] = o;
    }
}

// ---------------------------------------------------------------------------
// GEMM core: D[feat][token] = W x A^T. 128x128 tile, BK=64, double-buffered
// LDS (2x32KB) with cross-barrier in-flight loads (T3/T4 minimum 2-phase):
// stage(t+1) -> s_waitcnt vmcnt(8) [tile t's 8 wave-loads complete, 8 newer
// stay in flight] -> s_barrier -> ds_read+32xMFMA(t) -> fence+s_barrier
// [readers done before buffer reuse]. Never vmcnt(0) mid-loop.
// LDS rows are 128B / 8 granules of 16B; swizzle key = row&7 (full 32-bank
// span; same conflict degree as the measured-0-conflict BK=32 layout).
// ---------------------------------------------------------------------------
#define GEMM_CORE(Aptr, Wptr)                                                           \
    __shared__ ushort_t As[2][128 * 64];                                                \
    __shared__ ushort_t Bs[2][128 * 64];                                                \
    const int tid = threadIdx.x;                                                        \
    const int lane = tid & 63, wid = tid >> 6;                                          \
    const int quad = lane >> 4, l15 = lane & 15;                                        \
    const int m0 = blockIdx.x * 128, n0 = blockIdx.y * 128;                             \
    const int wy = wid >> 1, wx = wid & 1;                                              \
    const int srow = lane >> 3, sg = lane & 7;                                          \
    floatx4 acc[4][4];                                                                  \
    _Pragma("unroll") for (int i = 0; i < 4; ++i)                                       \
        _Pragma("unroll") for (int j = 0; j < 4; ++j)                                   \
            _Pragma("unroll") for (int r = 0; r < 4; ++r) acc[i][j][r] = 0.f;           \
    _Pragma("unroll") for (int j = 0; j < 4; ++j) {                                     \
        const int t = wid * 4 + j;                                                      \
        const int row = t * 8 + srow;                                                   \
        const int g = sg ^ (row & 7);                                                   \
        gl_lds16(Aptr + (size_t)(m0 + row) * DDIM + g * 8,                              \
                 (char*)&As[0][0] + t * 1024);                                          \
        gl_lds16(Wptr + (size_t)(n0 + row) * DDIM + g * 8,                              \
                 (char*)&Bs[0][0] + t * 1024);                                          \
    }                                                                                   \
    _Pragma("unroll") for (int kt = 0; kt < 8; ++kt) {                                  \
        const int cur = kt & 1;                                                         \
        if (kt < 7) {                                                                   \
            _Pragma("unroll") for (int j = 0; j < 4; ++j) {                             \
                const int t = wid * 4 + j;                                              \
                const int row = t * 8 + srow;                                           \
                const int g = sg ^ (row & 7);                                           \
                gl_lds16(Aptr + (size_t)(m0 + row) * DDIM + (kt + 1) * 64 + g * 8,      \
                         (char*)&As[cur ^ 1][0] + t * 1024);                            \
                gl_lds16(Wptr + (size_t)(n0 + row) * DDIM + (kt + 1) * 64 + g * 8,      \
                         (char*)&Bs[cur ^ 1][0] + t * 1024);                            \
            }                                                                           \
            asm volatile("s_waitcnt vmcnt(8)" ::: "memory");                            \
        } else {                                                                        \
            asm volatile("s_waitcnt vmcnt(0)" ::: "memory");                            \
        }                                                                               \
        __builtin_amdgcn_s_barrier();                                                   \
        _Pragma("unroll") for (int h = 0; h < 2; ++h) {                                 \
            short8 aw[4], bt[4];                                                        \
            _Pragma("unroll") for (int fi = 0; fi < 4; ++fi) {                          \
                const int r = wy * 64 + fi * 16 + l15;                                  \
                aw[fi] = *(const short8*)((const char*)&Bs[cur][0] + r * 128 +          \
                                          (((h * 4 + quad) ^ (r & 7)) << 4));           \
            }                                                                           \
            _Pragma("unroll") for (int ti = 0; ti < 4; ++ti) {                          \
                const int r = wx * 64 + ti * 16 + l15;                                  \
                bt[ti] = *(const short8*)((const char*)&As[cur][0] + r * 128 +          \
                                          (((h * 4 + quad) ^ (r & 7)) << 4));           \
            }                                                                           \
            _Pragma("unroll") for (int fi = 0; fi < 4; ++fi)                            \
                _Pragma("unroll") for (int ti = 0; ti < 4; ++ti)                        \
                    acc[fi][ti] = __builtin_amdgcn_mfma_f32_16x16x32_bf16(              \
                        aw[fi], bt[ti], acc[fi][ti], 0, 0, 0);                          \
        }                                                                               \
        asm volatile("" ::: "memory");                                                  \
        __builtin_amdgcn_s_barrier();                                                   \
    }

// QKV projection -> Q,K bf16 [token][512]; V fp16 [token][512] (z==2)
__global__ __launch_bounds__(256)
__attribute__((amdgpu_waves_per_eu(2, 2)))
void gemm_qkv(
    const ushort_t* __restrict__ A,
    const ushort_t* __restrict__ W0, const ushort_t* __restrict__ W1,
    const ushort_t* __restrict__ W2,
    const float* __restrict__ b0, const float* __restrict__ b1,
    const float* __restrict__ b2,
    ushort_t* __restrict__ o0, ushort_t* __restrict__ o1, ushort_t* __restrict__ o2) {
    const ushort_t* W; const float* bias; ushort_t* dst;
    if (blockIdx.z == 0)      { W = W0; bias = b0; dst = o0; }
    else if (blockIdx.z == 1) { W = W1; bias = b1; dst = o1; }
    else                      { W = W2; bias = b2; dst = o2; }
    const bool as_f16 = (blockIdx.z == 2);
    GEMM_CORE(A, W)
    #pragma unroll
    for (int fi = 0; fi < 4; ++fi) {
        const int f = n0 + wy * 64 + fi * 16 + quad * 4;
        const float4 b4 = *(const float4*)&bias[f];
        #pragma unroll
        for (int ti = 0; ti < 4; ++ti) {
            const int token = m0 + wx * 64 + ti * 16 + l15;
            const float v0 = acc[fi][ti][0] + b4.x, v1 = acc[fi][ti][1] + b4.y;
            const float v2 = acc[fi][ti][2] + b4.z, v3 = acc[fi][ti][3] + b4.w;
            uint2 v;
            if (as_f16) { v.x = pkh(v0, v1);  v.y = pkh(v2, v3); }
            else        { v.x = pkbf(v0, v1); v.y = pkbf(v2, v3); }
            *(uint2*)&dst[(size_t)token * DDIM + f] = v;
        }
    }
}

// Output projection -> fp32 [token][512]
__global__ __launch_bounds__(256)
__attribute__((amdgpu_waves_per_eu(2, 2)))
void gemm_out(
    const ushort_t* __restrict__ A, const ushort_t* __restrict__ Wo,
    const float* __restrict__ bo, float* __restrict__ dst) {
    GEMM_CORE(A, Wo)
    #pragma unroll
    for (int fi = 0; fi < 4; ++fi) {
        const int f = n0 + wy * 64 + fi * 16 + quad * 4;
        const float4 b4 = *(const float4*)&bo[f];
        #pragma unroll
        for (int ti = 0; ti < 4; ++ti) {
            const int token = m0 + wx * 64 + ti * 16 + l15;
            float4 v;
            v.x = acc[fi][ti][0] + b4.x; v.y = acc[fi][ti][1] + b4.y;
            v.z = acc[fi][ti][2] + b4.z; v.w = acc[fi][ti][3] + b4.w;
            *(float4*)&dst[(size_t)token * DDIM + f] = v;
        }
    }
}

// ---------------------------------------------------------------------------
// Persistent-KV MFMA attention, 32x32 MFMA + in-register P.
//  * __launch_bounds__(512) + amdgpu_waves_per_eu(2,2): LDS (128KB) caps at
//    1 block/CU = 2 waves/SIMD -> 256-VGPR budget (round-1's 128-VGPR cap
//    caused scratch spill: FETCH +23MB, +35us stall).
//  * kti-outer / qt-inner loop: one kti's kf/vf live at a time.
// P path: S^T = K.Q^T via mfma_f32_32x32x16_bf16; P packed fp16 in-register
// (cvt_pkrtz) + permlane32_swap(w0,w2)/(w1,w3) -> PV B-operand; no P LDS.
// ---------------------------------------------------------------------------
__global__ __launch_bounds__(512)
__attribute__((amdgpu_waves_per_eu(2, 2)))
void attn_fused(
    const ushort_t* __restrict__ Qg, const ushort_t* __restrict__ Kg,
    const ushort_t* __restrict__ Vtg, const ushort_t* __restrict__ Tg,
    ushort_t* __restrict__ aout) {
    __shared__ ushort_t Ks[512 * 64];   // 64KB: row kj, 128B, 8x16B grans, gran g = global g^key(kj)
    __shared__ ushort_t Vs[64 * 512];   // 64KB: row d, 1024B, 64 grans, gran g = global g^key(d)

    const int tid = threadIdx.x, lane = tid & 63, wid = tid >> 6;
    const int l31 = lane & 31, hl = lane >> 5;
    const int h = blockIdx.x, b = blockIdx.y;
    const float K1 = 0.18033688f;       // 0.125 * log2(e)

    // ---- stage K + V^T (once) ----
    #pragma unroll
    for (int j = 0; j < 8; ++j) {
        const int t = wid * 8 + j;
        {   // K rows t*8 .. t*8+7 (1KB per wave-load)
            const int row = t * 8 + (lane >> 3);
            const int key = (row & 7) ^ ((row >> 3) & 7);
            const int g = (lane & 7) ^ key;
            gl_lds16(Kg + (size_t)(b * NN + row) * DDIM + h * DK + g * 8,
                     (char*)Ks + t * 1024);
        }
        {   // V^T row d = t (1KB per wave-load)
            const int key = (t & 7) ^ ((t >> 3) & 7);
            const int g = lane ^ key;
            gl_lds16(Vtg + (size_t)((b * HH + h) * DK + t) * NN + g * 8,
                     (char*)Vs + t * 1024);
        }
    }

    // ---- Q fragments (B-operand: n=q=lane&31, k=dk=(lane>>5)*8+j) ----
    short8 bq[2][4];
    #pragma unroll
    for (int qt = 0; qt < 2; ++qt) {
        const ushort_t* qp =
            Qg + (size_t)(b * NN + wid * 64 + qt * 32 + l31) * DDIM + h * DK + hl * 8;
        #pragma unroll
        for (int st = 0; st < 4; ++st) bq[qt][st] = *(const short8*)(qp + st * 16);
    }

    float lsum[2] = {0.f, 0.f};
    floatx16 O[2][2];                    // [qt][dt], C: col=q, row=d
    #pragma unroll
    for (int qt = 0; qt < 2; ++qt)
        #pragma unroll
        for (int dt = 0; dt < 2; ++dt)
            #pragma unroll
            for (int r = 0; r < 16; ++r) O[qt][dt][r] = 0.f;

    __syncthreads();   // the only barrier

    for (int kt = 0; kt < 8; ++kt) {
        // T prefetch: tv[qt][kti][g] covers k = kt*64 + kti*32 + g*8 + hl*4 + 0..3
        uint2 tv[2][2][4];
        #pragma unroll
        for (int qt = 0; qt < 2; ++qt) {
            const ushort_t* tp =
                Tg + (size_t)(b * NN + wid * 64 + qt * 32 + l31) * NN + kt * 64 + hl * 4;
            #pragma unroll
            for (int kti = 0; kti < 2; ++kti)
                #pragma unroll
                for (int g = 0; g < 4; ++g)
                    tv[qt][kti][g] = *(const uint2*)(tp + kti * 32 + g * 8);
        }

        #pragma unroll
        for (int kti = 0; kti < 2; ++kti) {
            // K fragments (A: m=k-row=lane&31(+base), k=dk=(lane>>5)*8+j)
            short8 kf[4];
            {
                const int row = kt * 64 + kti * 32 + l31;
                const int key = (row & 7) ^ ((row >> 3) & 7);
                #pragma unroll
                for (int st = 0; st < 4; ++st)
                    kf[st] = *(const short8*)((const char*)Ks + row * 128 +
                                              (((st * 2 + hl) ^ key) << 4));
            }
            // V^T fragments (A: m=d=lane&31(+dt*32), k=(lane>>5)*8+j)
            half8 vf[2][2];   // [dt][ks]
            #pragma unroll
            for (int dt = 0; dt < 2; ++dt) {
                const int d = dt * 32 + l31;
                const int key = (d & 7) ^ ((d >> 3) & 7);
                #pragma unroll
                for (int ks = 0; ks < 2; ++ks)
                    vf[dt][ks] = *(const half8*)((const char*)Vs + d * 1024 +
                        (((kt * 8 + kti * 4 + ks * 2 + hl) ^ key) << 4));
            }

            #pragma unroll
            for (int qt = 0; qt < 2; ++qt) {
                // S^T tile [32k x 32q] = K.Q^T
                floatx16 S;
                #pragma unroll
                for (int r = 0; r < 16; ++r) S[r] = 0.f;
                __builtin_amdgcn_s_setprio(1);
                #pragma unroll
                for (int st = 0; st < 4; ++st)
                    S = __builtin_amdgcn_mfma_f32_32x32x16_bf16(
                        kf[st], bq[qt][st], S, 0, 0, 0);
                __builtin_amdgcn_s_setprio(0);

                float ls = 0.f;
                #pragma unroll
                for (int ks = 0; ks < 2; ++ks) {       // 16-k PV step
                    float pp[8];
                    #pragma unroll
                    for (int gg = 0; gg < 2; ++gg) {
                        const uint2 tg = tv[qt][kti][ks * 2 + gg];
                        const float t0 = h2f((ushort_t)tg.x);
                        const float t1 = h2f((ushort_t)(tg.x >> 16));
                        const float t2 = h2f((ushort_t)tg.y);
                        const float t3 = h2f((ushort_t)(tg.y >> 16));
                        const int sb = ks * 8 + gg * 4;
                        pp[gg * 4 + 0] = exp2f(S[sb + 0] * K1 + t0);
                        pp[gg * 4 + 1] = exp2f(S[sb + 1] * K1 + t1);
                        pp[gg * 4 + 2] = exp2f(S[sb + 2] * K1 + t2);
                        pp[gg * 4 + 3] = exp2f(S[sb + 3] * K1 + t3);
                        ls += (pp[gg * 4 + 0] + pp[gg * 4 + 1]) +
                              (pp[gg * 4 + 2] + pp[gg * 4 + 3]);
                    }
                    // pack own 8 P vals to fp16, half-exchange to B layout:
                    // lane's pp[gg*4+r] holds k_off = 8*gg + 4*hl + r.
                    // B needs k = 8*hl + j. swap(w0,w2) -> (word0, word2);
                    // swap(w1,w3) -> (word1, word3).
                    uint_t w0 = pkh(pp[0], pp[1]);   // own pk01
                    uint_t w1 = pkh(pp[2], pp[3]);   // own pk23
                    uint_t w2 = pkh(pp[4], pp[5]);   // own pk45
                    uint_t w3 = pkh(pp[6], pp[7]);   // own pk67
                    auto r02 = __builtin_amdgcn_permlane32_swap(w0, w2, false, false);
                    auto r13 = __builtin_amdgcn_permlane32_swap(w1, w3, false, false);
                    uint4 uu;
                    uu.x = r02[0];   // word0 = {w0.lo, w2.lo}
                    uu.y = r13[0];   // word1 = {w1.lo, w3.lo}
                    uu.z = r02[1];   // word2 = {w0.hi, w2.hi}
                    uu.w = r13[1];   // word3 = {w1.hi, w3.hi}
                    const half8 bp = __builtin_bit_cast(half8, uu);

                    __builtin_amdgcn_s_setprio(1);
                    #pragma unroll
                    for (int dt = 0; dt < 2; ++dt)
                        O[qt][dt] = __builtin_amdgcn_mfma_f32_32x32x16_f16(
                            vf[dt][ks], bp, O[qt][dt], 0, 0, 0);
                    __builtin_amdgcn_s_setprio(0);
                }
                lsum[qt] += ls;
            }
        }
    }

    // ---- epilogue: reduce l over lane halves, normalize, write bf16 ----
    #pragma unroll
    for (int qt = 0; qt < 2; ++qt) {
        float l = lsum[qt];
        l += __shfl_xor(l, 32);
        const float inv = 1.0f / l;
        const size_t orow =
            (size_t)(b * NN + wid * 64 + qt * 32 + l31) * DDIM + h * DK;
        #pragma unroll
        for (int dt = 0; dt < 2; ++dt)
            #pragma unroll
            for (int g = 0; g < 4; ++g) {
                const int d = dt * 32 + g * 8 + hl * 4;
                uint2 ov;
                ov.x = pkbf(O[qt][dt][g * 4 + 0] * inv, O[qt][dt][g * 4 + 1] * inv);
                ov.y = pkbf(O[qt][dt][g * 4 + 2] * inv, O[qt][dt][g * 4 + 3] * inv);
                *(uint2*)&aout[orow + d] = ov;
            }
    }
}

extern "C" void kernel_launch(void* const* d_in, const int* in_sizes, int n_in,
                              void* d_out, int out_size, void* d_ws, size_t ws_size,
                              hipStream_t stream) {
    const float* x    = (const float*)d_in[0];
    const float* dist = (const float*)d_in[1];
    const float* Wq   = (const float*)d_in[2];
    const float* bq   = (const float*)d_in[3];
    const float* Wk   = (const float*)d_in[4];
    const float* bk   = (const float*)d_in[5];
    const float* Wv   = (const float*)d_in[6];
    const float* bv   = (const float*)d_in[7];
    const float* Wo   = (const float*)d_in[8];
    const float* bo   = (const float*)d_in[9];
    const float* dw   = (const float*)d_in[10];
    float* out = (float*)d_out;

    const size_t NELT = (size_t)BB * NN * DDIM;   // 8388608
    ushort_t* xb  = (ushort_t*)d_ws;              // x bf16; aliased by ab later
    ushort_t* wqb = xb + NELT;
    ushort_t* wkb = wqb + DDIM * DDIM;
    ushort_t* wvb = wkb + DDIM * DDIM;
    ushort_t* wob = wvb + DDIM * DDIM;
    ushort_t* qb  = wob + DDIM * DDIM;
    ushort_t* kb  = qb + NELT;
    ushort_t* vb  = kb + NELT;                    // fp16
    ushort_t* vt  = vb + NELT;                    // fp16, transposed
    ushort_t* Tm  = vt + NELT;                    // fp16 bias matrix
    ushort_t* ab  = xb;                           // alias: xb dead after gemm_qkv

    cvt_bf16<<<4096, 256, 0, stream>>>(x, xb, (int)(NELT / 8));
    cvt_w4<<<dim3(128, 4), 256, 0, stream>>>(Wq, Wk, Wv, Wo, wqb, wkb, wvb, wob);
    bias_half<<<4096, 256, 0, stream>>>(dist, dw, Tm, (int)(NELT / 8));

    gemm_qkv<<<dim3(128, 4, 3), 256, 0, stream>>>(xb, wqb, wkb, wvb, bq, bk, bv,
                                                  qb, kb, vb);
    transp_v<<<dim3(8, 256), 256, 0, stream>>>(vb, vt);
    attn_fused<<<dim3(HH, BB), 512, 0, stream>>>(qb, kb, vt, Tm, ab);
    gemm_out<<<dim3(128, 4), 256, 0, stream>>>(ab, wob, bo, out);
}

// Round 5
// 231.757 us; speedup vs baseline: 1.1702x; 1.0276x over previous
//
#include <hip/hip_runtime.h>
#include <hip/hip_fp16.h>
#include <math.h>
#include <stdint.h>

#define BB 32
#define NN 512
#define DDIM 512
#define HH 8
#define DK 64

typedef __attribute__((ext_vector_type(8))) short short8;
typedef __attribute__((ext_vector_type(8))) _Float16 half8;
typedef __attribute__((ext_vector_type(4))) float floatx4;
typedef __attribute__((ext_vector_type(16))) float floatx16;
typedef unsigned short ushort_t;
typedef unsigned int uint_t;

// async global->LDS, 16B/lane; LDS dest = wave-uniform base + lane*16
__device__ __forceinline__ void gl_lds16(const void* g, void* l) {
    __builtin_amdgcn_global_load_lds(
        (const __attribute__((address_space(1))) uint_t*)g,
        (__attribute__((address_space(3))) uint_t*)l,
        16, 0, 0);
}

__device__ __forceinline__ ushort_t f2bf(float f) {  // RNE fp32->bf16
    uint_t u = __builtin_bit_cast(uint_t, f);
    u += 0x7fff + ((u >> 16) & 1);
    return (ushort_t)(u >> 16);
}

__device__ __forceinline__ uint_t pkbf(float a, float b) {
    return (uint_t)f2bf(a) | ((uint_t)f2bf(b) << 16);
}

__device__ __forceinline__ uint_t pkh(float a, float b) {  // 2xf32 -> f16x2 (RTZ, 1 inst)
    return __builtin_bit_cast(uint_t, __builtin_amdgcn_cvt_pkrtz(a, b));
}

__device__ __forceinline__ float h2f(ushort_t u) {
    return __half2float(__ushort_as_half(u));
}

// ---------------------------------------------------------------------------
// merged prep kernel: blockIdx.x partition
//   [0, 4096)      : x f32 -> bf16            (4096*256*8 = 8388608 elems)
//   [4096, 8192)   : dist -> fp16 T bias      (same count)
//   [8192, 8704)   : 4 weight matrices -> bf16 (512 blocks: 128 per matrix)
// ---------------------------------------------------------------------------
__global__ __launch_bounds__(256) void prep_all(
    const float* __restrict__ x, const float* __restrict__ dist,
    const float* __restrict__ dw,
    const float* __restrict__ Wq, const float* __restrict__ Wk,
    const float* __restrict__ Wv, const float* __restrict__ Wo,
    ushort_t* __restrict__ xb, ushort_t* __restrict__ Tm,
    ushort_t* __restrict__ wqb, ushort_t* __restrict__ wkb,
    ushort_t* __restrict__ wvb, ushort_t* __restrict__ wob) {
    const int bx = blockIdx.x;
    if (bx < 4096) {
        const int i = bx * 256 + threadIdx.x;
        const float4 a = ((const float4*)x)[i * 2 + 0];
        const float4 b = ((const float4*)x)[i * 2 + 1];
        uint4 o;
        o.x = pkbf(a.x, a.y); o.y = pkbf(a.z, a.w);
        o.z = pkbf(b.x, b.y); o.w = pkbf(b.z, b.w);
        *(uint4*)(xb + (size_t)i * 8) = o;
    } else if (bx < 8192) {
        __shared__ float dws[21];
        if (threadIdx.x < 21) dws[threadIdx.x] = (dw[threadIdx.x] - 3.0f) * 1.44269504f;
        __syncthreads();
        const int i = (bx - 4096) * 256 + threadIdx.x;
        float dv[8];
        { const float4 a = ((const float4*)dist)[i * 2 + 0];
          const float4 b = ((const float4*)dist)[i * 2 + 1];
          dv[0]=a.x; dv[1]=a.y; dv[2]=a.z; dv[3]=a.w;
          dv[4]=b.x; dv[5]=b.y; dv[6]=b.z; dv[7]=b.w; }
        ushort_t h[8];
        #pragma unroll
        for (int j = 0; j < 8; ++j) {
            int bin = (int)(dv[j] / 5.0f);
            bin = bin < 0 ? 0 : (bin > 20 ? 20 : bin);
            h[j] = __half_as_ushort(__float2half(dws[bin]));
        }
        uint4 o;
        o.x = (uint_t)h[0] | ((uint_t)h[1] << 16);
        o.y = (uint_t)h[2] | ((uint_t)h[3] << 16);
        o.z = (uint_t)h[4] | ((uint_t)h[5] << 16);
        o.w = (uint_t)h[6] | ((uint_t)h[7] << 16);
        *(uint4*)(Tm + (size_t)i * 8) = o;
    } else {
        const int bw = bx - 8192;            // [0,512)
        const int w = bw >> 7;               // matrix id
        const float* s; ushort_t* d;
        if (w == 0)      { s = Wq; d = wqb; }
        else if (w == 1) { s = Wk; d = wkb; }
        else if (w == 2) { s = Wv; d = wvb; }
        else             { s = Wo; d = wob; }
        const int i = (bw & 127) * 256 + threadIdx.x;
        const float4 a = ((const float4*)s)[i * 2 + 0];
        const float4 b = ((const float4*)s)[i * 2 + 1];
        uint4 o;
        o.x = pkbf(a.x, a.y); o.y = pkbf(a.z, a.w);
        o.z = pkbf(b.x, b.y); o.w = pkbf(b.z, b.w);
        *(uint4*)(d + (size_t)i * 8) = o;
    }
}

// ---------------------------------------------------------------------------
// GEMM core (round-2 proven version): D[feat][token] = W x A^T. 128x128 tile,
// BK=32, global_load_lds, XOR chunk swizzle, 2x16KB LDS.
// ---------------------------------------------------------------------------
#define GEMM_CORE(Aptr, Wptr)                                                           \
    __shared__ ushort_t As[128 * 32];                                                   \
    __shared__ ushort_t Bs[128 * 32];                                                   \
    const int tid = threadIdx.x;                                                        \
    const int lane = tid & 63, wid = tid >> 6;                                          \
    const int quad = lane >> 4, l15 = lane & 15;                                        \
    const int m0 = blockIdx.x * 128, n0 = blockIdx.y * 128;                             \
    const int wy = wid >> 1, wx = wid & 1;                                              \
    floatx4 acc[4][4];                                                                  \
    _Pragma("unroll") for (int i = 0; i < 4; ++i)                                       \
        _Pragma("unroll") for (int j = 0; j < 4; ++j)                                   \
            _Pragma("unroll") for (int r = 0; r < 4; ++r) acc[i][j][r] = 0.f;           \
    for (int k0 = 0; k0 < DDIM; k0 += 32) {                                             \
        __syncthreads();                                                                \
        _Pragma("unroll") for (int j = 0; j < 4; ++j) {                                 \
            const int t = wid * 4 + j;                                                  \
            const int rowi = ((t & 7) << 4) + (lane >> 2);                              \
            const int cd = (lane & 3) ^ ((rowi >> 1) & 3);                              \
            if (t < 8)                                                                  \
                gl_lds16(Aptr + (size_t)(m0 + rowi) * DDIM + k0 + cd * 8,               \
                         (char*)As + ((t & 7) << 10));                                  \
            else                                                                        \
                gl_lds16(Wptr + (size_t)(n0 + rowi) * DDIM + k0 + cd * 8,               \
                         (char*)Bs + ((t & 7) << 10));                                  \
        }                                                                               \
        __syncthreads();                                                                \
        short8 aw[4], bt[4];                                                            \
        _Pragma("unroll") for (int fi = 0; fi < 4; ++fi) {                              \
            const int r = wy * 64 + fi * 16 + l15;                                      \
            aw[fi] = *(const short8*)((const char*)Bs + r * 64 +                        \
                                      ((quad ^ ((r >> 1) & 3)) << 4));                  \
        }                                                                               \
        _Pragma("unroll") for (int ti = 0; ti < 4; ++ti) {                              \
            const int r = wx * 64 + ti * 16 + l15;                                      \
            bt[ti] = *(const short8*)((const char*)As + r * 64 +                        \
                                      ((quad ^ ((r >> 1) & 3)) << 4));                  \
        }                                                                               \
        _Pragma("unroll") for (int fi = 0; fi < 4; ++fi)                                \
            _Pragma("unroll") for (int ti = 0; ti < 4; ++ti)                            \
                acc[fi][ti] = __builtin_amdgcn_mfma_f32_16x16x32_bf16(                  \
                    aw[fi], bt[ti], acc[fi][ti], 0, 0, 0);                              \
    }

// QKV projection -> Q,K bf16 [token][512]; V (z==2) written DIRECTLY
// TRANSPOSED as fp16 Vt[(b*8+h)*64+d][token] (replaces transp_v kernel).
__global__ __launch_bounds__(256) void gemm_qkv(
    const ushort_t* __restrict__ A,
    const ushort_t* __restrict__ W0, const ushort_t* __restrict__ W1,
    const ushort_t* __restrict__ W2,
    const float* __restrict__ b0, const float* __restrict__ b1,
    const float* __restrict__ b2,
    ushort_t* __restrict__ o0, ushort_t* __restrict__ o1, ushort_t* __restrict__ o2) {
    const ushort_t* W; const float* bias; ushort_t* dst;
    if (blockIdx.z == 0)      { W = W0; bias = b0; dst = o0; }
    else if (blockIdx.z == 1) { W = W1; bias = b1; dst = o1; }
    else                      { W = W2; bias = b2; dst = o2; }
    const bool as_f16 = (blockIdx.z == 2);
    GEMM_CORE(A, W)
    if (as_f16) {
        // V transposed write. Global feature F = n0+wy*64+fi*16+quad*4+r;
        // one wave covers F-range of exactly one head hh. b = m0>>9 const
        // per block (m0 mult of 128; 128-token tile within one b).
        const int hh = (n0 + wy * 64) >> 6;
        const size_t vrow0 = ((size_t)((m0 >> 9) * HH + hh)) * DK;
        const int q0 = (m0 & 511) + wx * 64;
        #pragma unroll
        for (int fi = 0; fi < 4; ++fi) {
            const int f = n0 + wy * 64 + fi * 16 + quad * 4;
            const float4 b4 = *(const float4*)&bias[f];
            const int d = fi * 16 + quad * 4;
            #pragma unroll
            for (int ti = 0; ti < 4; ++ti) {
                const int q = q0 + ti * 16 + l15;
                dst[(vrow0 + d + 0) * NN + q] =
                    __half_as_ushort(__float2half(acc[fi][ti][0] + b4.x));
                dst[(vrow0 + d + 1) * NN + q] =
                    __half_as_ushort(__float2half(acc[fi][ti][1] + b4.y));
                dst[(vrow0 + d + 2) * NN + q] =
                    __half_as_ushort(__float2half(acc[fi][ti][2] + b4.z));
                dst[(vrow0 + d + 3) * NN + q] =
                    __half_as_ushort(__float2half(acc[fi][ti][3] + b4.w));
            }
        }
    } else {
        #pragma unroll
        for (int fi = 0; fi < 4; ++fi) {
            const int f = n0 + wy * 64 + fi * 16 + quad * 4;
            const float4 b4 = *(const float4*)&bias[f];
            #pragma unroll
            for (int ti = 0; ti < 4; ++ti) {
                const int token = m0 + wx * 64 + ti * 16 + l15;
                const float v0 = acc[fi][ti][0] + b4.x, v1 = acc[fi][ti][1] + b4.y;
                const float v2 = acc[fi][ti][2] + b4.z, v3 = acc[fi][ti][3] + b4.w;
                uint2 v;
                v.x = pkbf(v0, v1); v.y = pkbf(v2, v3);
                *(uint2*)&dst[(size_t)token * DDIM + f] = v;
            }
        }
    }
}

// Output projection -> fp32 [token][512]
__global__ __launch_bounds__(256) void gemm_out(
    const ushort_t* __restrict__ A, const ushort_t* __restrict__ Wo,
    const float* __restrict__ bo, float* __restrict__ dst) {
    GEMM_CORE(A, Wo)
    #pragma unroll
    for (int fi = 0; fi < 4; ++fi) {
        const int f = n0 + wy * 64 + fi * 16 + quad * 4;
        const float4 b4 = *(const float4*)&bo[f];
        #pragma unroll
        for (int ti = 0; ti < 4; ++ti) {
            const int token = m0 + wx * 64 + ti * 16 + l15;
            float4 v;
            v.x = acc[fi][ti][0] + b4.x; v.y = acc[fi][ti][1] + b4.y;
            v.z = acc[fi][ti][2] + b4.z; v.w = acc[fi][ti][3] + b4.w;
            *(float4*)&dst[(size_t)token * DDIM + f] = v;
        }
    }
}

// ---------------------------------------------------------------------------
// Persistent-KV MFMA attention, 32x32 MFMA + in-register P (unchanged from
// round 3; spill-free at 256-VGPR budget via waves_per_eu(2,2)).
// ---------------------------------------------------------------------------
__global__ __launch_bounds__(512)
__attribute__((amdgpu_waves_per_eu(2, 2)))
void attn_fused(
    const ushort_t* __restrict__ Qg, const ushort_t* __restrict__ Kg,
    const ushort_t* __restrict__ Vtg, const ushort_t* __restrict__ Tg,
    ushort_t* __restrict__ aout) {
    __shared__ ushort_t Ks[512 * 64];   // 64KB: row kj, 128B, 8x16B grans, gran g = global g^key(kj)
    __shared__ ushort_t Vs[64 * 512];   // 64KB: row d, 1024B, 64 grans, gran g = global g^key(d)

    const int tid = threadIdx.x, lane = tid & 63, wid = tid >> 6;
    const int l31 = lane & 31, hl = lane >> 5;
    const int h = blockIdx.x, b = blockIdx.y;
    const float K1 = 0.18033688f;       // 0.125 * log2(e)

    // ---- stage K + V^T (once) ----
    #pragma unroll
    for (int j = 0; j < 8; ++j) {
        const int t = wid * 8 + j;
        {   // K rows t*8 .. t*8+7 (1KB per wave-load)
            const int row = t * 8 + (lane >> 3);
            const int key = (row & 7) ^ ((row >> 3) & 7);
            const int g = (lane & 7) ^ key;
            gl_lds16(Kg + (size_t)(b * NN + row) * DDIM + h * DK + g * 8,
                     (char*)Ks + t * 1024);
        }
        {   // V^T row d = t (1KB per wave-load)
            const int key = (t & 7) ^ ((t >> 3) & 7);
            const int g = lane ^ key;
            gl_lds16(Vtg + (size_t)((b * HH + h) * DK + t) * NN + g * 8,
                     (char*)Vs + t * 1024);
        }
    }

    // ---- Q fragments (B-operand: n=q=lane&31, k=dk=(lane>>5)*8+j) ----
    short8 bq[2][4];
    #pragma unroll
    for (int qt = 0; qt < 2; ++qt) {
        const ushort_t* qp =
            Qg + (size_t)(b * NN + wid * 64 + qt * 32 + l31) * DDIM + h * DK + hl * 8;
        #pragma unroll
        for (int st = 0; st < 4; ++st) bq[qt][st] = *(const short8*)(qp + st * 16);
    }

    float lsum[2] = {0.f, 0.f};
    floatx16 O[2][2];                    // [qt][dt], C: col=q, row=d
    #pragma unroll
    for (int qt = 0; qt < 2; ++qt)
        #pragma unroll
        for (int dt = 0; dt < 2; ++dt)
            #pragma unroll
            for (int r = 0; r < 16; ++r) O[qt][dt][r] = 0.f;

    __syncthreads();   // the only barrier

    for (int kt = 0; kt < 8; ++kt) {
        // T prefetch: tv[qt][kti][g] covers k = kt*64 + kti*32 + g*8 + hl*4 + 0..3
        uint2 tv[2][2][4];
        #pragma unroll
        for (int qt = 0; qt < 2; ++qt) {
            const ushort_t* tp =
                Tg + (size_t)(b * NN + wid * 64 + qt * 32 + l31) * NN + kt * 64 + hl * 4;
            #pragma unroll
            for (int kti = 0; kti < 2; ++kti)
                #pragma unroll
                for (int g = 0; g < 4; ++g)
                    tv[qt][kti][g] = *(const uint2*)(tp + kti * 32 + g * 8);
        }

        #pragma unroll
        for (int kti = 0; kti < 2; ++kti) {
            // K fragments (A: m=k-row=lane&31(+base), k=dk=(lane>>5)*8+j)
            short8 kf[4];
            {
                const int row = kt * 64 + kti * 32 + l31;
                const int key = (row & 7) ^ ((row >> 3) & 7);
                #pragma unroll
                for (int st = 0; st < 4; ++st)
                    kf[st] = *(const short8*)((const char*)Ks + row * 128 +
                                              (((st * 2 + hl) ^ key) << 4));
            }
            // V^T fragments (A: m=d=lane&31(+dt*32), k=(lane>>5)*8+j)
            half8 vf[2][2];   // [dt][ks]
            #pragma unroll
            for (int dt = 0; dt < 2; ++dt) {
                const int d = dt * 32 + l31;
                const int key = (d & 7) ^ ((d >> 3) & 7);
                #pragma unroll
                for (int ks = 0; ks < 2; ++ks)
                    vf[dt][ks] = *(const half8*)((const char*)Vs + d * 1024 +
                        (((kt * 8 + kti * 4 + ks * 2 + hl) ^ key) << 4));
            }

            #pragma unroll
            for (int qt = 0; qt < 2; ++qt) {
                // S^T tile [32k x 32q] = K.Q^T
                floatx16 S;
                #pragma unroll
                for (int r = 0; r < 16; ++r) S[r] = 0.f;
                __builtin_amdgcn_s_setprio(1);
                #pragma unroll
                for (int st = 0; st < 4; ++st)
                    S = __builtin_amdgcn_mfma_f32_32x32x16_bf16(
                        kf[st], bq[qt][st], S, 0, 0, 0);
                __builtin_amdgcn_s_setprio(0);

                float ls = 0.f;
                #pragma unroll
                for (int ks = 0; ks < 2; ++ks) {       // 16-k PV step
                    float pp[8];
                    #pragma unroll
                    for (int gg = 0; gg < 2; ++gg) {
                        const uint2 tg = tv[qt][kti][ks * 2 + gg];
                        const float t0 = h2f((ushort_t)tg.x);
                        const float t1 = h2f((ushort_t)(tg.x >> 16));
                        const float t2 = h2f((ushort_t)tg.y);
                        const float t3 = h2f((ushort_t)(tg.y >> 16));
                        const int sb = ks * 8 + gg * 4;
                        pp[gg * 4 + 0] = exp2f(S[sb + 0] * K1 + t0);
                        pp[gg * 4 + 1] = exp2f(S[sb + 1] * K1 + t1);
                        pp[gg * 4 + 2] = exp2f(S[sb + 2] * K1 + t2);
                        pp[gg * 4 + 3] = exp2f(S[sb + 3] * K1 + t3);
                        ls += (pp[gg * 4 + 0] + pp[gg * 4 + 1]) +
                              (pp[gg * 4 + 2] + pp[gg * 4 + 3]);
                    }
                    // pack own 8 P vals to fp16, half-exchange to B layout:
                    // lane's pp[gg*4+r] holds k_off = 8*gg + 4*hl + r.
                    // B needs k = 8*hl + j. swap(w0,w2) -> (word0, word2);
                    // swap(w1,w3) -> (word1, word3).
                    uint_t w0 = pkh(pp[0], pp[1]);   // own pk01
                    uint_t w1 = pkh(pp[2], pp[3]);   // own pk23
                    uint_t w2 = pkh(pp[4], pp[5]);   // own pk45
                    uint_t w3 = pkh(pp[6], pp[7]);   // own pk67
                    auto r02 = __builtin_amdgcn_permlane32_swap(w0, w2, false, false);
                    auto r13 = __builtin_amdgcn_permlane32_swap(w1, w3, false, false);
                    uint4 uu;
                    uu.x = r02[0];   // word0 = {w0.lo, w2.lo}
                    uu.y = r13[0];   // word1 = {w1.lo, w3.lo}
                    uu.z = r02[1];   // word2 = {w0.hi, w2.hi}
                    uu.w = r13[1];   // word3 = {w1.hi, w3.hi}
                    const half8 bp = __builtin_bit_cast(half8, uu);

                    __builtin_amdgcn_s_setprio(1);
                    #pragma unroll
                    for (int dt = 0; dt < 2; ++dt)
                        O[qt][dt] = __builtin_amdgcn_mfma_f32_32x32x16_f16(
                            vf[dt][ks], bp, O[qt][dt], 0, 0, 0);
                    __builtin_amdgcn_s_setprio(0);
                }
                lsum[qt] += ls;
            }
        }
    }

    // ---- epilogue: reduce l over lane halves, normalize, write bf16 ----
    #pragma unroll
    for (int qt = 0; qt < 2; ++qt) {
        float l = lsum[qt];
        l += __shfl_xor(l, 32);
        const float inv = 1.0f / l;
        const size_t orow =
            (size_t)(b * NN + wid * 64 + qt * 32 + l31) * DDIM + h * DK;
        #pragma unroll
        for (int dt = 0; dt < 2; ++dt)
            #pragma unroll
            for (int g = 0; g < 4; ++g) {
                const int d = dt * 32 + g * 8 + hl * 4;
                uint2 ov;
                ov.x = pkbf(O[qt][dt][g * 4 + 0] * inv, O[qt][dt][g * 4 + 1] * inv);
                ov.y = pkbf(O[qt][dt][g * 4 + 2] * inv, O[qt][dt][g * 4 + 3] * inv);
                *(uint2*)&aout[orow + d] = ov;
            }
    }
}

extern "C" void kernel_launch(void* const* d_in, const int* in_sizes, int n_in,
                              void* d_out, int out_size, void* d_ws, size_t ws_size,
                              hipStream_t stream) {
    const float* x    = (const float*)d_in[0];
    const float* dist = (const float*)d_in[1];
    const float* Wq   = (const float*)d_in[2];
    const float* bq   = (const float*)d_in[3];
    const float* Wk   = (const float*)d_in[4];
    const float* bk   = (const float*)d_in[5];
    const float* Wv   = (const float*)d_in[6];
    const float* bv   = (const float*)d_in[7];
    const float* Wo   = (const float*)d_in[8];
    const float* bo   = (const float*)d_in[9];
    const float* dw   = (const float*)d_in[10];
    float* out = (float*)d_out;

    const size_t NELT = (size_t)BB * NN * DDIM;   // 8388608
    ushort_t* xb  = (ushort_t*)d_ws;              // x bf16; aliased by ab later
    ushort_t* wqb = xb + NELT;
    ushort_t* wkb = wqb + DDIM * DDIM;
    ushort_t* wvb = wkb + DDIM * DDIM;
    ushort_t* wob = wvb + DDIM * DDIM;
    ushort_t* qb  = wob + DDIM * DDIM;
    ushort_t* kb  = qb + NELT;
    ushort_t* vt  = kb + NELT;                    // fp16, transposed (written by gemm_qkv)
    ushort_t* Tm  = vt + NELT;                    // fp16 bias matrix
    ushort_t* ab  = xb;                           // alias: xb dead after gemm_qkv

    prep_all<<<8704, 256, 0, stream>>>(x, dist, dw, Wq, Wk, Wv, Wo,
                                       xb, Tm, wqb, wkb, wvb, wob);
    gemm_qkv<<<dim3(128, 4, 3), 256, 0, stream>>>(xb, wqb, wkb, wvb, bq, bk, bv,
                                                  qb, kb, vt);
    attn_fused<<<dim3(HH, BB), 512, 0, stream>>>(qb, kb, vt, Tm, ab);
    gemm_out<<<dim3(128, 4), 256, 0, stream>>>(ab, wob, bo, out);
}